// Round 1
// baseline (21974.777 us; speedup 1.0000x reference)
//
#include <hip/hip_runtime.h>
#include <math.h>

// S=512, B=128, H=1024. Output [B,T,2] fp32, T=512.
// GRU feedback is h only => (1) sequential scan (split-fp16, fp32-equivalent),
// (2) batched scores+softmax GEMM, (3) context GEMM fused with 2-wide projection.
//
// R4 change (correctness): R3's relaxed publication raced (harness failure,
// absmax 0.0156 — stale Hallh lines). Restore sound cross-XCD semantics:
//   producer: flag fetch_add is RELEASE/agent (emits buffer_wbl2 sc1 — dirty
//             local-XCD L2 lines written back before flag is visible);
//   consumer: acquire fence is AGENT scope (emits buffer_inv sc1 — stale
//             L1/L2 lines discarded before the plain Hallh reads).

typedef _Float16 half_t;
typedef _Float16 half8 __attribute__((ext_vector_type(8)));
typedef _Float16 half4v __attribute__((ext_vector_type(4)));
typedef float f32x4 __attribute__((ext_vector_type(4)));

#define B_ 128
#define H_ 1024
#define S_ 512

__device__ __forceinline__ float sigm(float x) {
  return 1.f / (1.f + __expf(-x));
}
__device__ __forceinline__ float tanh_fast(float x) {
  x = fminf(fmaxf(x, -15.f), 15.f);
  float e2 = __expf(2.f * x);
  return (e2 - 1.f) / (e2 + 1.f);
}

// ---------------- pack combined gate weights, split fp16 hi+lo ---------------
// Packed row p = j*4 + g: g0: Wir+Whr, g1: Wiz+Whz, g2: Win, g3: Whn.
// Per ntile (16 rows): half8 unit u = kq*64 + lane holds W[row nt*16+(lane&15)]
// [k = kq*32 + (lane>>4)*8 .. +7].
__global__ void k_pack(const float* __restrict__ Wih, const float* __restrict__ Whh,
                       half_t* __restrict__ Wpkh, half_t* __restrict__ Wpkl) {
  int tid = blockIdx.x * 256 + threadIdx.x;   // [0, 524288)
  int nt_g = tid >> 11;                       // [0,256)
  int u    = tid & 2047;
  int kq = u >> 6, lane = u & 63;
  int p = nt_g * 16 + (lane & 15);
  int j = p >> 2, g = p & 3;
  int k0 = kq * 32 + (lane >> 4) * 8;
  float v[8];
  if (g == 0) {
    const float* p0 = Wih + (size_t)j * H_ + k0;
    const float* p1 = Whh + (size_t)j * H_ + k0;
#pragma unroll
    for (int i = 0; i < 8; ++i) v[i] = p0[i] + p1[i];
  } else if (g == 1) {
    const float* p0 = Wih + (size_t)(1024 + j) * H_ + k0;
    const float* p1 = Whh + (size_t)(1024 + j) * H_ + k0;
#pragma unroll
    for (int i = 0; i < 8; ++i) v[i] = p0[i] + p1[i];
  } else if (g == 2) {
    const float* p0 = Wih + (size_t)(2048 + j) * H_ + k0;
#pragma unroll
    for (int i = 0; i < 8; ++i) v[i] = p0[i];
  } else {
    const float* p0 = Whh + (size_t)(2048 + j) * H_ + k0;
#pragma unroll
    for (int i = 0; i < 8; ++i) v[i] = p0[i];
  }
  half8 hv, lv;
#pragma unroll
  for (int i = 0; i < 8; ++i) {
    half_t h = (half_t)v[i];
    hv[i] = h;
    lv[i] = (half_t)(v[i] - (float)h);
  }
  size_t dst = (size_t)nt_g * 16384 + (size_t)u * 8;
  *(half8*)(Wpkh + dst) = hv;
  *(half8*)(Wpkl + dst) = lv;
}

// ---------------- fp32 -> fp16 conversion of enc_outputs --------------------
__global__ void k_enc(const float* __restrict__ src, half_t* __restrict__ dst) {
  size_t i = (size_t)blockIdx.x * 256 + threadIdx.x;
  const float4* s4 = (const float4*)src;
  float4 v = s4[i];
  half4v h;
  h[0] = (half_t)v.x; h[1] = (half_t)v.y; h[2] = (half_t)v.z; h[3] = (half_t)v.w;
  *(half4v*)(dst + i * 4) = h;
}

// ---------------- exact step 0 (x = 0, h = h0), fp64 accumulate --------------
__global__ void k_step0(const float* __restrict__ h0, const float* __restrict__ Whh,
                        const float* __restrict__ bih, const float* __restrict__ bhh,
                        float* __restrict__ Hst1, half_t* __restrict__ Hallh,
                        half_t* __restrict__ Halll) {
  __shared__ float wr[1024], wz[1024], wn[1024];
  int j = blockIdx.x;
  int b = threadIdx.x;
  for (int k = b; k < 1024; k += 128) {
    wr[k] = Whh[(size_t)j * H_ + k];
    wz[k] = Whh[(size_t)(1024 + j) * H_ + k];
    wn[k] = Whh[(size_t)(2048 + j) * H_ + k];
  }
  __syncthreads();
  const float* hb = h0 + (size_t)b * H_;
  double sr = 0.0, sz = 0.0, sn = 0.0;
  for (int k = 0; k < 1024; ++k) {
    double h = (double)hb[k];
    sr += h * (double)wr[k]; sz += h * (double)wz[k]; sn += h * (double)wn[k];
  }
  float r = sigm((float)sr + bih[j] + bhh[j]);
  float z = sigm((float)sz + bih[1024 + j] + bhh[1024 + j]);
  float n = tanhf(bih[2048 + j] + r * ((float)sn + bhh[2048 + j]));
  float h1 = (1.f - z) * n + z * hb[j];
  Hst1[(size_t)b * H_ + j] = h1;
  half_t hi = (half_t)h1;
  Hallh[(size_t)(1 * B_ + b) * H_ + j] = hi;
  Halll[(size_t)(1 * B_ + b) * H_ + j] = (half_t)(h1 - (float)hi);
}

// ---------------- persistent GRU scan, steps 1..511, split-fp16 --------------
// 256 blocks x 512 thr. bid: ab = bid&3 (batch group, 2 slices), jb = bid>>2
// (16 j's). Wave wv: ntl = wv&3 (4-j subtile), sll = wv>>2 -> slice ab*2+sll.
// W-hi (64 packed rows x 1024k) in LDS 128KB; W-lo (wave's 16 rows) in VGPRs.
// h published via sc1 relaxed-agent atomic stores; flag add carries RELEASE
// (buffer_wbl2 sc1); consumer spin is followed by an AGENT acquire fence
// (buffer_inv sc1) so the plain Hallh reads cannot hit stale lines.
__global__ void __launch_bounds__(512, 2)
k_gru(const half_t* __restrict__ Wpkh, const half_t* __restrict__ Wpkl,
      const float* __restrict__ Hst1, half_t* __restrict__ Hallh,
      half_t* __restrict__ Halll, const float* __restrict__ bih,
      const float* __restrict__ bhh, int* __restrict__ flags) {
  extern __shared__ char smem[];
  half_t* smW = (half_t*)smem;
  const int bid = blockIdx.x;
  const int ab = bid & 3, jb = bid >> 2;
  const int tid = threadIdx.x;
  const int wv = tid >> 6, lane = tid & 63;
  const int ntl = wv & 3, sll = wv >> 2;
  const int sl = ab * 2 + sll;
  const int jl = lane & 15, quad = lane >> 4, jj = jl >> 2;

  { // W-hi -> LDS: 4 ntiles (jb*4 .. +3), 65536 halves = 8192 uint4
    const uint4* src = (const uint4*)(Wpkh + (size_t)jb * 65536);
    uint4* dst = (uint4*)smem;
    for (int i = tid; i < 8192; i += 512) dst[i] = src[i];
  }

  // W-lo -> registers (this wave's ntile)
  half8 Wlo[32];
  {
    const half_t* src = Wpkl + (size_t)(jb * 4 + ntl) * 16384 + (size_t)lane * 8;
#pragma unroll
    for (int kq = 0; kq < 32; ++kq)
      Wlo[kq] = *(const half8*)(src + (size_t)kq * 512);
  }

  const int j = jb * 16 + ntl * 4 + jj;
  const float br  = bih[j]        + bhh[j];
  const float bz  = bih[1024 + j] + bhh[1024 + j];
  const float bxn = bih[2048 + j];
  const float bhn = bhh[2048 + j];

  float hold[4];
#pragma unroll
  for (int r = 0; r < 4; ++r)
    hold[r] = Hst1[(size_t)(sl * 16 + quad * 4 + r) * H_ + j];

  const int bA = sl * 16 + jl;             // A-operand batch row (m = lane&15)
  const half_t* smB = smW + (size_t)ntl * 16384 + (size_t)lane * 8;
  const int qb = lane & 48;                // quad*16
  const int j0 = jb * 16 + ntl * 4;

  __syncthreads();

  for (int t = 1; t < 512; ++t) {
    if (t >= 2) {
      int* f = flags + t * 8 + sl;
      while (__hip_atomic_load(f, __ATOMIC_RELAXED, __HIP_MEMORY_SCOPE_AGENT) < 64)
        __builtin_amdgcn_s_sleep(1);
      __builtin_amdgcn_fence(__ATOMIC_ACQUIRE, "agent");
    }
    const half_t* pH = Hallh + ((size_t)t * B_ + bA) * H_ + quad * 8;
    const half_t* pL = Halll + ((size_t)t * B_ + bA) * H_ + quad * 8;

    f32x4 acc_a = {0.f,0.f,0.f,0.f};
    f32x4 acc_b = {0.f,0.f,0.f,0.f};
    f32x4 acc_c = {0.f,0.f,0.f,0.f};
#pragma unroll
    for (int kq = 0; kq < 32; ++kq) {
      uint4 ahu = *(const uint4*)(pH + kq * 32);
      uint4 alu = *(const uint4*)(pL + kq * 32);
      half8 ah = __builtin_bit_cast(half8, ahu);
      half8 al = __builtin_bit_cast(half8, alu);
      half8 bh = *(const half8*)(smB + (size_t)kq * 512);
      acc_a = __builtin_amdgcn_mfma_f32_16x16x32_f16(ah, bh,      acc_a, 0, 0, 0);
      acc_b = __builtin_amdgcn_mfma_f32_16x16x32_f16(al, bh,      acc_b, 0, 0, 0);
      acc_c = __builtin_amdgcn_mfma_f32_16x16x32_f16(ah, Wlo[kq], acc_c, 0, 0, 0);
    }

    half_t* Hh = Hallh + (size_t)(t + 1) * (B_ * H_);
    half_t* Hl = Halll + (size_t)(t + 1) * (B_ * H_);
#pragma unroll
    for (int r = 0; r < 4; ++r) {
      float v = acc_a[r] + acc_b[r] + acc_c[r];
      int base = lane & 60;
      float g0 = __shfl(v, base | 0);
      float g1 = __shfl(v, base | 1);
      float g2 = __shfl(v, base | 2);
      float g3 = __shfl(v, base | 3);
      float rr = sigm(g0 + br);
      float zz = sigm(g1 + bz);
      float nn = tanh_fast(g2 + bxn + rr * (g3 + bhn));
      float h = (1.f - zz) * nn + zz * hold[r];
      hold[r] = h;
      half_t hi = (half_t)h;
      half_t lo = (half_t)(h - (float)hi);
      unsigned hb16 = (unsigned)__builtin_bit_cast(unsigned short, hi);
      unsigned lb16 = (unsigned)__builtin_bit_cast(unsigned short, lo);
      unsigned hp0 = __shfl(hb16, qb | 0) | (__shfl(hb16, qb | 4) << 16);
      unsigned hp1 = __shfl(hb16, qb | 8) | (__shfl(hb16, qb | 12) << 16);
      unsigned lp0 = __shfl(lb16, qb | 0) | (__shfl(lb16, qb | 4) << 16);
      unsigned lp1 = __shfl(lb16, qb | 8) | (__shfl(lb16, qb | 12) << 16);
      if (jl == 0) {
        int brow = sl * 16 + quad * 4 + r;
        unsigned long long hp = (unsigned long long)hp0 | ((unsigned long long)hp1 << 32);
        unsigned long long lp = (unsigned long long)lp0 | ((unsigned long long)lp1 << 32);
        __hip_atomic_store((unsigned long long*)(Hh + (size_t)brow * H_ + j0), hp,
                           __ATOMIC_RELAXED, __HIP_MEMORY_SCOPE_AGENT);
        __hip_atomic_store((unsigned long long*)(Hl + (size_t)brow * H_ + j0), lp,
                           __ATOMIC_RELAXED, __HIP_MEMORY_SCOPE_AGENT);
      }
    }
    __syncthreads();   // all waves' stores are vmcnt-drained at the barrier;
                       // the RELEASE below writes back any dirty L2 lines
                       // (buffer_wbl2 sc1) before the flag becomes visible.
    if (tid < 2)
      __hip_atomic_fetch_add(flags + (t + 1) * 8 + ab * 2 + tid, 1,
                             __ATOMIC_RELEASE, __HIP_MEMORY_SCOPE_AGENT);
  }
}

// ---------------- scores + softmax ------------------------------------------
__global__ void __launch_bounds__(512, 1)
k_scores(const half_t* __restrict__ Hallh, const half_t* __restrict__ enc16,
         const int* __restrict__ lengths, half_t* __restrict__ wbuf) {
  extern __shared__ char sm[];
  const int b = blockIdx.x, tt = blockIdx.y;
  const int tid = threadIdx.x;
  const int w = tid >> 6, lane = tid & 63;
  const int jl = lane & 15, quad = lane >> 4;
  const int t0 = tt * 128;
  const int len = lengths[b];

  f32x4 acc[32];
#pragma unroll
  for (int i = 0; i < 32; ++i) acc[i] = (f32x4){0.f,0.f,0.f,0.f};

  const half_t* Arow =
      Hallh + ((size_t)(1 + t0 + w * 16 + jl) * B_ + b) * H_ + quad * 8;

  uint4* smu = (uint4*)sm;
  const int s = tid;
  const uint4* grow = (const uint4*)(enc16 + ((size_t)s * B_ + b) * H_);
  uint4* dbase = smu + ((s >> 4) * 64 + (s & 15));

  { uint4* d = dbase; d[0] = grow[0]; d[16] = grow[1]; d[32] = grow[2]; d[48] = grow[3]; }
  uint4 a_cur = *(const uint4*)(Arow);
  __syncthreads();

  for (int kq = 0; kq < 32; ++kq) {
    const int buf = kq & 1;
    uint4 a_next;
    if (kq < 31) {
      const uint4* g = grow + (kq + 1) * 4;
      uint4* d = dbase + (buf ^ 1) * 2048;
      d[0] = g[0]; d[16] = g[1]; d[32] = g[2]; d[48] = g[3];
      a_next = *(const uint4*)(Arow + (kq + 1) * 32);
    }
    half8 av = __builtin_bit_cast(half8, a_cur);
    const half8* Bb = (const half8*)sm + buf * 2048 + lane;
#pragma unroll
    for (int nf = 0; nf < 32; ++nf)
      acc[nf] = __builtin_amdgcn_mfma_f32_16x16x32_f16(av, Bb[nf * 64], acc[nf], 0, 0, 0);
    a_cur = a_next;
    __syncthreads();
  }

#pragma unroll
  for (int r = 0; r < 4; ++r) {
    float vmax = -3.0e38f;
#pragma unroll
    for (int nf = 0; nf < 32; ++nf) {
      int scol = nf * 16 + jl;
      float v = (scol < len) ? acc[nf][r] : -3.0e38f;
      acc[nf][r] = v;
      vmax = fmaxf(vmax, v);
    }
#pragma unroll
    for (int off = 1; off < 16; off <<= 1) vmax = fmaxf(vmax, __shfl_xor(vmax, off, 64));
    float esum = 0.f;
#pragma unroll
    for (int nf = 0; nf < 32; ++nf) {
      float e = __expf(acc[nf][r] - vmax);
      acc[nf][r] = e;
      esum += e;
    }
#pragma unroll
    for (int off = 1; off < 16; off <<= 1) esum += __shfl_xor(esum, off, 64);
    float inv = 1.f / esum;
    const int t = t0 + w * 16 + quad * 4 + r;
    half_t* wrow = wbuf + ((size_t)b * S_ + t) * S_ + jl;
#pragma unroll
    for (int nf = 0; nf < 32; ++nf) wrow[nf * 16] = (half_t)(acc[nf][r] * inv);
  }
}

// ---------------- context GEMM + projection (context part) ------------------
__global__ void __launch_bounds__(512, 1)
k_ctx(const half_t* __restrict__ wbuf, const half_t* __restrict__ enc16,
      const float* __restrict__ Wp, float* __restrict__ out) {
  extern __shared__ char sm[];
  const int b = blockIdx.x, ht = blockIdx.y, tt = blockIdx.z;
  const int tid = threadIdx.x;
  const int w = tid >> 6, lane = tid & 63;
  const int jl = lane & 15, quad = lane >> 4;
  const int h0 = ht * 128, t0 = tt * 128;

  f32x4 acc[8];
#pragma unroll
  for (int i = 0; i < 8; ++i) acc[i] = (f32x4){0.f,0.f,0.f,0.f};

  const half_t* Arow = wbuf + ((size_t)b * S_ + t0 + w * 16 + jl) * S_ + quad * 8;
  const int s_l = tid >> 4, hc = tid & 15;
  const half_t* gsrc = enc16 + ((size_t)s_l * B_ + b) * H_ + h0 + hc * 8;
  half_t* sbase = (half_t*)sm;

  {
    uint4 v = *(const uint4*)gsrc;
    half8 hv = __builtin_bit_cast(half8, v);
#pragma unroll
    for (int i = 0; i < 8; ++i) {
      int h_l = hc * 8 + i;
      sbase[((h_l >> 4) * 64 + (s_l >> 3) * 16 + (h_l & 15)) * 8 + (s_l & 7)] = hv[i];
    }
  }
  uint4 a_cur = *(const uint4*)(Arow);
  __syncthreads();

  for (int kq = 0; kq < 16; ++kq) {
    const int buf = kq & 1;
    uint4 a_next;
    if (kq < 15) {
      uint4 v = *(const uint4*)(gsrc + (size_t)(kq + 1) * 32 * (B_ * H_));
      half8 hv = __builtin_bit_cast(half8, v);
      half_t* d = sbase + (buf ^ 1) * 4096;
#pragma unroll
      for (int i = 0; i < 8; ++i) {
        int h_l = hc * 8 + i;
        d[((h_l >> 4) * 64 + (s_l >> 3) * 16 + (h_l & 15)) * 8 + (s_l & 7)] = hv[i];
      }
      a_next = *(const uint4*)(Arow + (kq + 1) * 32);
    }
    half8 av = __builtin_bit_cast(half8, a_cur);
    const half8* Bb = (const half8*)sm + buf * 512 + lane;
#pragma unroll
    for (int nf = 0; nf < 8; ++nf)
      acc[nf] = __builtin_amdgcn_mfma_f32_16x16x32_f16(av, Bb[nf * 64], acc[nf], 0, 0, 0);
    a_cur = a_next;
    __syncthreads();
  }

  float wp0[8], wp1[8];
#pragma unroll
  for (int nf = 0; nf < 8; ++nf) {
    int h = h0 + nf * 16 + jl;
    wp0[nf] = Wp[h];
    wp1[nf] = Wp[2048 + h];
  }
#pragma unroll
  for (int r = 0; r < 4; ++r) {
    float y0 = 0.f, y1 = 0.f;
#pragma unroll
    for (int nf = 0; nf < 8; ++nf) {
      y0 += acc[nf][r] * wp0[nf];
      y1 += acc[nf][r] * wp1[nf];
    }
#pragma unroll
    for (int off = 1; off < 16; off <<= 1) {
      y0 += __shfl_xor(y0, off, 64);
      y1 += __shfl_xor(y1, off, 64);
    }
    if (jl == 0) {
      int t = t0 + w * 16 + quad * 4 + r;
      float* o = out + ((size_t)b * S_ + t) * 2;
      atomicAdd(o, y0);
      atomicAdd(o + 1, y1);
    }
  }
}

// ---------------- projection, h part + bias ----------------------------------
__global__ void k_ph(const half_t* __restrict__ Hallh, const float* __restrict__ Wp,
                     const float* __restrict__ bp, float* __restrict__ out) {
  const int t = blockIdx.x, b = blockIdx.y;
  const int tid = threadIdx.x;  // 128
  const half_t* hrow = Hallh + ((size_t)(1 + t) * B_ + b) * H_;
  float y0 = 0.f, y1 = 0.f;
#pragma unroll
  for (int k = 0; k < 8; ++k) {
    int h = tid + k * 128;
    float hv = (float)hrow[h];
    y0 += hv * Wp[1024 + h];
    y1 += hv * Wp[3072 + h];
  }
  for (int off = 1; off < 64; off <<= 1) {
    y0 += __shfl_xor(y0, off, 64);
    y1 += __shfl_xor(y1, off, 64);
  }
  __shared__ float red[4];
  int wid = tid >> 6;
  if ((tid & 63) == 0) { red[wid * 2] = y0; red[wid * 2 + 1] = y1; }
  __syncthreads();
  if (tid == 0) {
    size_t o = ((size_t)b * S_ + t) * 2;
    out[o]     += red[0] + red[2] + bp[0];
    out[o + 1] += red[1] + red[3] + bp[1];
  }
}

// ---------------- host launcher ----------------------------------------------
extern "C" void kernel_launch(void* const* d_in, const int* in_sizes, int n_in,
                              void* d_out, int out_size, void* d_ws, size_t ws_size,
                              hipStream_t stream) {
  const float* enc  = (const float*)d_in[0];
  const float* h0   = (const float*)d_in[1];
  const float* Wih  = (const float*)d_in[2];
  const float* Whh  = (const float*)d_in[3];
  const float* bih  = (const float*)d_in[4];
  const float* bhh  = (const float*)d_in[5];
  const float* Wp   = (const float*)d_in[6];
  const float* bp   = (const float*)d_in[7];
  const int* lengths = (const int*)d_in[8];
  float* out = (float*)d_out;

  char* ws = (char*)d_ws;
  size_t off = 0;
  auto alloc = [&](size_t bytes) -> char* {
    char* p = ws + off;
    off = (off + bytes + 511) & ~(size_t)511;
    return p;
  };
  half_t* Wpkh  = (half_t*)alloc((size_t)4096 * 1024 * 2);       // 8.39 MB
  half_t* Wpkl  = (half_t*)alloc((size_t)4096 * 1024 * 2);       // 8.39 MB
  int*    flags = (int*)alloc((size_t)513 * 8 * 4);
  float*  Hst1  = (float*)alloc((size_t)B_ * H_ * 4);            // 0.5 MB
  half_t* Hallh = (half_t*)alloc((size_t)513 * B_ * H_ * 2);     // 134.5 MB
  half_t* Halll = (half_t*)alloc((size_t)513 * B_ * H_ * 2);     // 134.5 MB
  half_t* enc16 = (half_t*)alloc((size_t)S_ * B_ * H_ * 2);      // 134.2 MB
  half_t* wbuf  = (half_t*)alloc((size_t)B_ * S_ * S_ * 2);      // 67.1 MB
  (void)ws_size; (void)in_sizes; (void)n_in;

  hipMemsetAsync(flags, 0, (size_t)513 * 8 * 4, stream);
  hipMemsetAsync(out, 0, (size_t)out_size * 4, stream);

  k_pack<<<2048, 256, 0, stream>>>(Wih, Whh, Wpkh, Wpkl);
  k_enc<<<65536, 256, 0, stream>>>(enc, enc16);
  k_step0<<<1024, 128, 0, stream>>>(h0, Whh, bih, bhh, Hst1, Hallh, Halll);

  hipFuncSetAttribute((const void*)k_gru,
                      hipFuncAttributeMaxDynamicSharedMemorySize, 131072);
  k_gru<<<256, 512, 131072, stream>>>(Wpkh, Wpkl, Hst1, Hallh, Halll, bih, bhh, flags);

  hipFuncSetAttribute((const void*)k_scores,
                      hipFuncAttributeMaxDynamicSharedMemorySize, 65536);
  k_scores<<<dim3(128, 4), 512, 65536, stream>>>(Hallh, enc16, lengths, wbuf);
  k_ctx<<<dim3(128, 8, 4), 512, 16384, stream>>>(wbuf, enc16, Wp, out);
  k_ph<<<dim3(512, 128), 128, 0, stream>>>(Hallh, Wp, bp, out);
}

// Round 2
// 12796.280 us; speedup vs baseline: 1.7173x; 1.7173x over previous
//
#include <hip/hip_runtime.h>
#include <math.h>

// S=512, B=128, H=1024. Output [B,T,2] fp32, T=512.
// GRU feedback is h only => (1) sequential scan (split-fp16, fp32-equivalent),
// (2) batched scores+softmax GEMM, (3) context GEMM fused with 2-wide projection.
//
// R5 change (perf, keeps R4's correctness): drop the per-step buffer_inv /
// buffer_wbl2 (42us/step). Data stores stay relaxed-agent sc1 atomics (these
// are performed at the agent coherence point by the gfx950 memory model — no
// wbl2 needed); the consumer now reads h[t] with relaxed-agent sc1 atomic
// LOADS (coherence point, no stale lines, no buffer_inv). To avoid 4x
// redundant MALL traffic from cache-bypassing reads, each block stages its
// A-operand (2 slices, hi+lo = 128 KB) into LDS once per step; W-hi moves
// from LDS to plain cached global streams (constant data -> staleness-free).
// LDS A-tile is XOR-swizzled (byte ^= (row&7)<<4) via swizzled *source*
// addressing + linear ds_write; reads apply the same involution.

typedef _Float16 half_t;
typedef _Float16 half8 __attribute__((ext_vector_type(8)));
typedef _Float16 half4v __attribute__((ext_vector_type(4)));
typedef float f32x4 __attribute__((ext_vector_type(4)));

#define B_ 128
#define H_ 1024
#define S_ 512

__device__ __forceinline__ float sigm(float x) {
  return 1.f / (1.f + __expf(-x));
}
__device__ __forceinline__ float tanh_fast(float x) {
  x = fminf(fmaxf(x, -15.f), 15.f);
  float e2 = __expf(2.f * x);
  return (e2 - 1.f) / (e2 + 1.f);
}

// ---------------- pack combined gate weights, split fp16 hi+lo ---------------
// Packed row p = j*4 + g: g0: Wir+Whr, g1: Wiz+Whz, g2: Win, g3: Whn.
// Per ntile (16 rows): half8 unit u = kq*64 + lane holds W[row nt*16+(lane&15)]
// [k = kq*32 + (lane>>4)*8 .. +7].
__global__ void k_pack(const float* __restrict__ Wih, const float* __restrict__ Whh,
                       half_t* __restrict__ Wpkh, half_t* __restrict__ Wpkl) {
  int tid = blockIdx.x * 256 + threadIdx.x;   // [0, 524288)
  int nt_g = tid >> 11;                       // [0,256)
  int u    = tid & 2047;
  int kq = u >> 6, lane = u & 63;
  int p = nt_g * 16 + (lane & 15);
  int j = p >> 2, g = p & 3;
  int k0 = kq * 32 + (lane >> 4) * 8;
  float v[8];
  if (g == 0) {
    const float* p0 = Wih + (size_t)j * H_ + k0;
    const float* p1 = Whh + (size_t)j * H_ + k0;
#pragma unroll
    for (int i = 0; i < 8; ++i) v[i] = p0[i] + p1[i];
  } else if (g == 1) {
    const float* p0 = Wih + (size_t)(1024 + j) * H_ + k0;
    const float* p1 = Whh + (size_t)(1024 + j) * H_ + k0;
#pragma unroll
    for (int i = 0; i < 8; ++i) v[i] = p0[i] + p1[i];
  } else if (g == 2) {
    const float* p0 = Wih + (size_t)(2048 + j) * H_ + k0;
#pragma unroll
    for (int i = 0; i < 8; ++i) v[i] = p0[i];
  } else {
    const float* p0 = Whh + (size_t)(2048 + j) * H_ + k0;
#pragma unroll
    for (int i = 0; i < 8; ++i) v[i] = p0[i];
  }
  half8 hv, lv;
#pragma unroll
  for (int i = 0; i < 8; ++i) {
    half_t h = (half_t)v[i];
    hv[i] = h;
    lv[i] = (half_t)(v[i] - (float)h);
  }
  size_t dst = (size_t)nt_g * 16384 + (size_t)u * 8;
  *(half8*)(Wpkh + dst) = hv;
  *(half8*)(Wpkl + dst) = lv;
}

// ---------------- fp32 -> fp16 conversion of enc_outputs --------------------
__global__ void k_enc(const float* __restrict__ src, half_t* __restrict__ dst) {
  size_t i = (size_t)blockIdx.x * 256 + threadIdx.x;
  const float4* s4 = (const float4*)src;
  float4 v = s4[i];
  half4v h;
  h[0] = (half_t)v.x; h[1] = (half_t)v.y; h[2] = (half_t)v.z; h[3] = (half_t)v.w;
  *(half4v*)(dst + i * 4) = h;
}

// ---------------- exact step 0 (x = 0, h = h0), fp64 accumulate --------------
__global__ void k_step0(const float* __restrict__ h0, const float* __restrict__ Whh,
                        const float* __restrict__ bih, const float* __restrict__ bhh,
                        float* __restrict__ Hst1, half_t* __restrict__ Hallh,
                        half_t* __restrict__ Halll) {
  __shared__ float wr[1024], wz[1024], wn[1024];
  int j = blockIdx.x;
  int b = threadIdx.x;
  for (int k = b; k < 1024; k += 128) {
    wr[k] = Whh[(size_t)j * H_ + k];
    wz[k] = Whh[(size_t)(1024 + j) * H_ + k];
    wn[k] = Whh[(size_t)(2048 + j) * H_ + k];
  }
  __syncthreads();
  const float* hb = h0 + (size_t)b * H_;
  double sr = 0.0, sz = 0.0, sn = 0.0;
  for (int k = 0; k < 1024; ++k) {
    double h = (double)hb[k];
    sr += h * (double)wr[k]; sz += h * (double)wz[k]; sn += h * (double)wn[k];
  }
  float r = sigm((float)sr + bih[j] + bhh[j]);
  float z = sigm((float)sz + bih[1024 + j] + bhh[1024 + j]);
  float n = tanhf(bih[2048 + j] + r * ((float)sn + bhh[2048 + j]));
  float h1 = (1.f - z) * n + z * hb[j];
  Hst1[(size_t)b * H_ + j] = h1;
  half_t hi = (half_t)h1;
  Hallh[(size_t)(1 * B_ + b) * H_ + j] = hi;
  Halll[(size_t)(1 * B_ + b) * H_ + j] = (half_t)(h1 - (float)hi);
}

// ---------------- persistent GRU scan, steps 1..511, split-fp16 --------------
// 256 blocks x 512 thr. bid: ab = bid&3 (batch group, 2 slices), jb = bid>>2
// (16 j's). Wave wv: ntl = wv&3 (4-j subtile), sll = wv>>2 -> slice ab*2+sll.
// Per step: block stages A (h[t] rows ab*32..+31, hi+lo, 128 KB) into LDS via
// relaxed-agent sc1 8B atomic loads (coherence-point reads) with XOR-swizzled
// source addressing; W-hi streams from global (cached; constant data); W-lo
// stays in AGPRs. h published via relaxed-agent sc1 atomic stores; flag add
// is relaxed after __syncthreads (vmcnt drained; sc1 stores already at the
// coherence point -> no wbl2/inv needed anywhere).
__global__ void __launch_bounds__(512, 2)
k_gru(const half_t* __restrict__ Wpkh, const half_t* __restrict__ Wpkl,
      const float* __restrict__ Hst1, half_t* __restrict__ Hallh,
      half_t* __restrict__ Halll, const float* __restrict__ bih,
      const float* __restrict__ bhh, int* __restrict__ flags) {
  extern __shared__ char smem[];           // 128 KB: A_hi[32][2048B] | A_lo
  const int bid = blockIdx.x;
  const int ab = bid & 3, jb = bid >> 2;
  const int tid = threadIdx.x;
  const int wv = tid >> 6, lane = tid & 63;
  const int ntl = wv & 3, sll = wv >> 2;
  const int sl = ab * 2 + sll;
  const int jl = lane & 15, quad = lane >> 4, jj = jl >> 2;

  // W-lo -> registers (this wave's ntile)
  half8 Wlo[32];
  {
    const half_t* src = Wpkl + (size_t)(jb * 4 + ntl) * 16384 + (size_t)lane * 8;
#pragma unroll
    for (int kq = 0; kq < 32; ++kq)
      Wlo[kq] = *(const half8*)(src + (size_t)kq * 512);
  }
  // W-hi global stream base (plain cached loads; constant data)
  const half_t* Wg = Wpkh + (size_t)(jb * 4 + ntl) * 16384 + (size_t)lane * 8;

  const int j = jb * 16 + ntl * 4 + jj;
  const float br  = bih[j]        + bhh[j];
  const float bz  = bih[1024 + j] + bhh[1024 + j];
  const float bxn = bih[2048 + j];
  const float bhn = bhh[2048 + j];

  float hold[4];
#pragma unroll
  for (int r = 0; r < 4; ++r)
    hold[r] = Hst1[(size_t)(sl * 16 + quad * 4 + r) * H_ + j];

  const int qb = lane & 48;                // quad*16
  const int j0 = jb * 16 + ntl * 4;

  // A-read bases: logical (row = sll*16+jl, colbyte = quad*16 + kq*64),
  // swizzled LDS offset = row*2048 + ((quad*16 | kq*64) ^ ((jl&7)<<4)).
  // Split: bits4-5 fold into the base; bit6 flips kq parity -> even/odd bases.
  const int arow = sll * 16 + jl;
  const int a0   = arow * 2048 + ((quad * 16) ^ ((jl & 3) << 4));
  const int sx   = (jl >> 2) & 1;
  const char* pAhE = smem + a0 + sx * 64;          // even kq
  const char* pAhO = smem + a0 - sx * 64;          // odd  kq
  const char* pAlE = pAhE + 65536;
  const char* pAlO = pAhO + 65536;

  // stage addressing: unit u8 = c*512 + tid (8B units), row r = u8>>8,
  // in-row byte = (u8&255)*8, source col = in-row ^ ((r&7)<<4).
  const int so   = (tid & 255) * 8;
  const int r_lo = tid >> 8;               // 0 or 1

  for (int t = 1; t < 512; ++t) {
    if (t >= 2) {
      int* f = flags + t * 8 + ab * 2;
      while (__hip_atomic_load(f, __ATOMIC_RELAXED, __HIP_MEMORY_SCOPE_AGENT) < 64)
        __builtin_amdgcn_s_sleep(1);
      while (__hip_atomic_load(f + 1, __ATOMIC_RELAXED, __HIP_MEMORY_SCOPE_AGENT) < 64)
        __builtin_amdgcn_s_sleep(1);
      __builtin_amdgcn_fence(__ATOMIC_ACQUIRE, "workgroup");
    }
    // ---- stage A(t): 128 KB via sc1 coherent 8B loads, linear ds_write ----
    {
      const size_t tb = (size_t)((size_t)t * B_ + ab * 32) * 2048;  // bytes
      unsigned long long hv[16], lv[16];
#pragma unroll
      for (int c = 0; c < 16; ++c) {
        const int r = c * 2 + r_lo;
        const size_t srcoff = tb + (size_t)r * 2048 + (size_t)(so ^ ((r & 7) << 4));
        hv[c] = __hip_atomic_load((unsigned long long*)((char*)Hallh + srcoff),
                                  __ATOMIC_RELAXED, __HIP_MEMORY_SCOPE_AGENT);
        lv[c] = __hip_atomic_load((unsigned long long*)((char*)Halll + srcoff),
                                  __ATOMIC_RELAXED, __HIP_MEMORY_SCOPE_AGENT);
      }
#pragma unroll
      for (int c = 0; c < 16; ++c) {
        *(unsigned long long*)(smem + (size_t)(c * 512 + tid) * 8) = hv[c];
        *(unsigned long long*)(smem + 65536 + (size_t)(c * 512 + tid) * 8) = lv[c];
      }
    }
    __syncthreads();

    f32x4 acc_a = {0.f,0.f,0.f,0.f};
    f32x4 acc_b = {0.f,0.f,0.f,0.f};
    f32x4 acc_c = {0.f,0.f,0.f,0.f};
#pragma unroll
    for (int kq = 0; kq < 32; ++kq) {
      const char* pA = (kq & 1) ? pAhO : pAhE;
      const char* pL = (kq & 1) ? pAlO : pAlE;
      half8 ah = *(const half8*)(pA + kq * 64);
      half8 al = *(const half8*)(pL + kq * 64);
      half8 bh = *(const half8*)(Wg + (size_t)kq * 512);
      acc_a = __builtin_amdgcn_mfma_f32_16x16x32_f16(ah, bh,      acc_a, 0, 0, 0);
      acc_b = __builtin_amdgcn_mfma_f32_16x16x32_f16(al, bh,      acc_b, 0, 0, 0);
      acc_c = __builtin_amdgcn_mfma_f32_16x16x32_f16(ah, Wlo[kq], acc_c, 0, 0, 0);
    }

    half_t* Hh = Hallh + (size_t)(t + 1) * (B_ * H_);
    half_t* Hl = Halll + (size_t)(t + 1) * (B_ * H_);
#pragma unroll
    for (int r = 0; r < 4; ++r) {
      float v = acc_a[r] + acc_b[r] + acc_c[r];
      int base = lane & 60;
      float g0 = __shfl(v, base | 0);
      float g1 = __shfl(v, base | 1);
      float g2 = __shfl(v, base | 2);
      float g3 = __shfl(v, base | 3);
      float rr = sigm(g0 + br);
      float zz = sigm(g1 + bz);
      float nn = tanh_fast(g2 + bxn + rr * (g3 + bhn));
      float h = (1.f - zz) * nn + zz * hold[r];
      hold[r] = h;
      half_t hi = (half_t)h;
      half_t lo = (half_t)(h - (float)hi);
      unsigned hb16 = (unsigned)__builtin_bit_cast(unsigned short, hi);
      unsigned lb16 = (unsigned)__builtin_bit_cast(unsigned short, lo);
      unsigned hp0 = __shfl(hb16, qb | 0) | (__shfl(hb16, qb | 4) << 16);
      unsigned hp1 = __shfl(hb16, qb | 8) | (__shfl(hb16, qb | 12) << 16);
      unsigned lp0 = __shfl(lb16, qb | 0) | (__shfl(lb16, qb | 4) << 16);
      unsigned lp1 = __shfl(lb16, qb | 8) | (__shfl(lb16, qb | 12) << 16);
      if (jl == 0) {
        int brow = sl * 16 + quad * 4 + r;
        unsigned long long hp = (unsigned long long)hp0 | ((unsigned long long)hp1 << 32);
        unsigned long long lp = (unsigned long long)lp0 | ((unsigned long long)lp1 << 32);
        __hip_atomic_store((unsigned long long*)(Hh + (size_t)brow * H_ + j0), hp,
                           __ATOMIC_RELAXED, __HIP_MEMORY_SCOPE_AGENT);
        __hip_atomic_store((unsigned long long*)(Hl + (size_t)brow * H_ + j0), lp,
                           __ATOMIC_RELAXED, __HIP_MEMORY_SCOPE_AGENT);
      }
    }
    __syncthreads();   // drains vmcnt: all waves' sc1 stores performed at the
                       // agent coherence point before the flag is bumped.
    if (tid < 2)
      __hip_atomic_fetch_add(flags + (t + 1) * 8 + ab * 2 + tid, 1,
                             __ATOMIC_RELAXED, __HIP_MEMORY_SCOPE_AGENT);
  }
}

// ---------------- scores + softmax ------------------------------------------
__global__ void __launch_bounds__(512, 1)
k_scores(const half_t* __restrict__ Hallh, const half_t* __restrict__ enc16,
         const int* __restrict__ lengths, half_t* __restrict__ wbuf) {
  extern __shared__ char sm[];
  const int b = blockIdx.x, tt = blockIdx.y;
  const int tid = threadIdx.x;
  const int w = tid >> 6, lane = tid & 63;
  const int jl = lane & 15, quad = lane >> 4;
  const int t0 = tt * 128;
  const int len = lengths[b];

  f32x4 acc[32];
#pragma unroll
  for (int i = 0; i < 32; ++i) acc[i] = (f32x4){0.f,0.f,0.f,0.f};

  const half_t* Arow =
      Hallh + ((size_t)(1 + t0 + w * 16 + jl) * B_ + b) * H_ + quad * 8;

  uint4* smu = (uint4*)sm;
  const int s = tid;
  const uint4* grow = (const uint4*)(enc16 + ((size_t)s * B_ + b) * H_);
  uint4* dbase = smu + ((s >> 4) * 64 + (s & 15));

  { uint4* d = dbase; d[0] = grow[0]; d[16] = grow[1]; d[32] = grow[2]; d[48] = grow[3]; }
  uint4 a_cur = *(const uint4*)(Arow);
  __syncthreads();

  for (int kq = 0; kq < 32; ++kq) {
    const int buf = kq & 1;
    uint4 a_next;
    if (kq < 31) {
      const uint4* g = grow + (kq + 1) * 4;
      uint4* d = dbase + (buf ^ 1) * 2048;
      d[0] = g[0]; d[16] = g[1]; d[32] = g[2]; d[48] = g[3];
      a_next = *(const uint4*)(Arow + (kq + 1) * 32);
    }
    half8 av = __builtin_bit_cast(half8, a_cur);
    const half8* Bb = (const half8*)sm + buf * 2048 + lane;
#pragma unroll
    for (int nf = 0; nf < 32; ++nf)
      acc[nf] = __builtin_amdgcn_mfma_f32_16x16x32_f16(av, Bb[nf * 64], acc[nf], 0, 0, 0);
    a_cur = a_next;
    __syncthreads();
  }

#pragma unroll
  for (int r = 0; r < 4; ++r) {
    float vmax = -3.0e38f;
#pragma unroll
    for (int nf = 0; nf < 32; ++nf) {
      int scol = nf * 16 + jl;
      float v = (scol < len) ? acc[nf][r] : -3.0e38f;
      acc[nf][r] = v;
      vmax = fmaxf(vmax, v);
    }
#pragma unroll
    for (int off = 1; off < 16; off <<= 1) vmax = fmaxf(vmax, __shfl_xor(vmax, off, 64));
    float esum = 0.f;
#pragma unroll
    for (int nf = 0; nf < 32; ++nf) {
      float e = __expf(acc[nf][r] - vmax);
      acc[nf][r] = e;
      esum += e;
    }
#pragma unroll
    for (int off = 1; off < 16; off <<= 1) esum += __shfl_xor(esum, off, 64);
    float inv = 1.f / esum;
    const int t = t0 + w * 16 + quad * 4 + r;
    half_t* wrow = wbuf + ((size_t)b * S_ + t) * S_ + jl;
#pragma unroll
    for (int nf = 0; nf < 32; ++nf) wrow[nf * 16] = (half_t)(acc[nf][r] * inv);
  }
}

// ---------------- context GEMM + projection (context part) ------------------
__global__ void __launch_bounds__(512, 1)
k_ctx(const half_t* __restrict__ wbuf, const half_t* __restrict__ enc16,
      const float* __restrict__ Wp, float* __restrict__ out) {
  extern __shared__ char sm[];
  const int b = blockIdx.x, ht = blockIdx.y, tt = blockIdx.z;
  const int tid = threadIdx.x;
  const int w = tid >> 6, lane = tid & 63;
  const int jl = lane & 15, quad = lane >> 4;
  const int h0 = ht * 128, t0 = tt * 128;

  f32x4 acc[8];
#pragma unroll
  for (int i = 0; i < 8; ++i) acc[i] = (f32x4){0.f,0.f,0.f,0.f};

  const half_t* Arow = wbuf + ((size_t)b * S_ + t0 + w * 16 + jl) * S_ + quad * 8;
  const int s_l = tid >> 4, hc = tid & 15;
  const half_t* gsrc = enc16 + ((size_t)s_l * B_ + b) * H_ + h0 + hc * 8;
  half_t* sbase = (half_t*)sm;

  {
    uint4 v = *(const uint4*)gsrc;
    half8 hv = __builtin_bit_cast(half8, v);
#pragma unroll
    for (int i = 0; i < 8; ++i) {
      int h_l = hc * 8 + i;
      sbase[((h_l >> 4) * 64 + (s_l >> 3) * 16 + (h_l & 15)) * 8 + (s_l & 7)] = hv[i];
    }
  }
  uint4 a_cur = *(const uint4*)(Arow);
  __syncthreads();

  for (int kq = 0; kq < 16; ++kq) {
    const int buf = kq & 1;
    uint4 a_next;
    if (kq < 15) {
      uint4 v = *(const uint4*)(gsrc + (size_t)(kq + 1) * 32 * (B_ * H_));
      half8 hv = __builtin_bit_cast(half8, v);
      half_t* d = sbase + (buf ^ 1) * 4096;
#pragma unroll
      for (int i = 0; i < 8; ++i) {
        int h_l = hc * 8 + i;
        d[((h_l >> 4) * 64 + (s_l >> 3) * 16 + (h_l & 15)) * 8 + (s_l & 7)] = hv[i];
      }
      a_next = *(const uint4*)(Arow + (kq + 1) * 32);
    }
    half8 av = __builtin_bit_cast(half8, a_cur);
    const half8* Bb = (const half8*)sm + buf * 512 + lane;
#pragma unroll
    for (int nf = 0; nf < 8; ++nf)
      acc[nf] = __builtin_amdgcn_mfma_f32_16x16x32_f16(av, Bb[nf * 64], acc[nf], 0, 0, 0);
    a_cur = a_next;
    __syncthreads();
  }

  float wp0[8], wp1[8];
#pragma unroll
  for (int nf = 0; nf < 8; ++nf) {
    int h = h0 + nf * 16 + jl;
    wp0[nf] = Wp[h];
    wp1[nf] = Wp[2048 + h];
  }
#pragma unroll
  for (int r = 0; r < 4; ++r) {
    float y0 = 0.f, y1 = 0.f;
#pragma unroll
    for (int nf = 0; nf < 8; ++nf) {
      y0 += acc[nf][r] * wp0[nf];
      y1 += acc[nf][r] * wp1[nf];
    }
#pragma unroll
    for (int off = 1; off < 16; off <<= 1) {
      y0 += __shfl_xor(y0, off, 64);
      y1 += __shfl_xor(y1, off, 64);
    }
    if (jl == 0) {
      int t = t0 + w * 16 + quad * 4 + r;
      float* o = out + ((size_t)b * S_ + t) * 2;
      atomicAdd(o, y0);
      atomicAdd(o + 1, y1);
    }
  }
}

// ---------------- projection, h part + bias ----------------------------------
__global__ void k_ph(const half_t* __restrict__ Hallh, const float* __restrict__ Wp,
                     const float* __restrict__ bp, float* __restrict__ out) {
  const int t = blockIdx.x, b = blockIdx.y;
  const int tid = threadIdx.x;  // 128
  const half_t* hrow = Hallh + ((size_t)(1 + t) * B_ + b) * H_;
  float y0 = 0.f, y1 = 0.f;
#pragma unroll
  for (int k = 0; k < 8; ++k) {
    int h = tid + k * 128;
    float hv = (float)hrow[h];
    y0 += hv * Wp[1024 + h];
    y1 += hv * Wp[3072 + h];
  }
  for (int off = 1; off < 64; off <<= 1) {
    y0 += __shfl_xor(y0, off, 64);
    y1 += __shfl_xor(y1, off, 64);
  }
  __shared__ float red[4];
  int wid = tid >> 6;
  if ((tid & 63) == 0) { red[wid * 2] = y0; red[wid * 2 + 1] = y1; }
  __syncthreads();
  if (tid == 0) {
    size_t o = ((size_t)b * S_ + t) * 2;
    out[o]     += red[0] + red[2] + bp[0];
    out[o + 1] += red[1] + red[3] + bp[1];
  }
}

// ---------------- host launcher ----------------------------------------------
extern "C" void kernel_launch(void* const* d_in, const int* in_sizes, int n_in,
                              void* d_out, int out_size, void* d_ws, size_t ws_size,
                              hipStream_t stream) {
  const float* enc  = (const float*)d_in[0];
  const float* h0   = (const float*)d_in[1];
  const float* Wih  = (const float*)d_in[2];
  const float* Whh  = (const float*)d_in[3];
  const float* bih  = (const float*)d_in[4];
  const float* bhh  = (const float*)d_in[5];
  const float* Wp   = (const float*)d_in[6];
  const float* bp   = (const float*)d_in[7];
  const int* lengths = (const int*)d_in[8];
  float* out = (float*)d_out;

  char* ws = (char*)d_ws;
  size_t off = 0;
  auto alloc = [&](size_t bytes) -> char* {
    char* p = ws + off;
    off = (off + bytes + 511) & ~(size_t)511;
    return p;
  };
  half_t* Wpkh  = (half_t*)alloc((size_t)4096 * 1024 * 2);       // 8.39 MB
  half_t* Wpkl  = (half_t*)alloc((size_t)4096 * 1024 * 2);       // 8.39 MB
  int*    flags = (int*)alloc((size_t)513 * 8 * 4);
  float*  Hst1  = (float*)alloc((size_t)B_ * H_ * 4);            // 0.5 MB
  half_t* Hallh = (half_t*)alloc((size_t)513 * B_ * H_ * 2);     // 134.5 MB
  half_t* Halll = (half_t*)alloc((size_t)513 * B_ * H_ * 2);     // 134.5 MB
  half_t* enc16 = (half_t*)alloc((size_t)S_ * B_ * H_ * 2);      // 134.2 MB
  half_t* wbuf  = (half_t*)alloc((size_t)B_ * S_ * S_ * 2);      // 67.1 MB
  (void)ws_size; (void)in_sizes; (void)n_in;

  hipMemsetAsync(flags, 0, (size_t)513 * 8 * 4, stream);
  hipMemsetAsync(out, 0, (size_t)out_size * 4, stream);

  k_pack<<<2048, 256, 0, stream>>>(Wih, Whh, Wpkh, Wpkl);
  k_enc<<<65536, 256, 0, stream>>>(enc, enc16);
  k_step0<<<1024, 128, 0, stream>>>(h0, Whh, bih, bhh, Hst1, Hallh, Halll);

  hipFuncSetAttribute((const void*)k_gru,
                      hipFuncAttributeMaxDynamicSharedMemorySize, 131072);
  k_gru<<<256, 512, 131072, stream>>>(Wpkh, Wpkl, Hst1, Hallh, Halll, bih, bhh, flags);

  hipFuncSetAttribute((const void*)k_scores,
                      hipFuncAttributeMaxDynamicSharedMemorySize, 65536);
  k_scores<<<dim3(128, 4), 512, 65536, stream>>>(Hallh, enc16, lengths, wbuf);
  k_ctx<<<dim3(128, 8, 4), 512, 16384, stream>>>(wbuf, enc16, Wp, out);
  k_ph<<<dim3(512, 128), 128, 0, stream>>>(Hallh, Wp, bp, out);
}

// Round 5
// 11545.095 us; speedup vs baseline: 1.9034x; 1.1084x over previous
//
#include <hip/hip_runtime.h>
#include <math.h>

// S=512, B=128, H=1024. Output [B,T,2] fp32, T=512.
// GRU feedback is h only => (1) sequential scan (split-fp16, fp32-equivalent),
// (2) batched scores+softmax GEMM, (3) context GEMM fused with 2-wide projection.
//
// R8 = R6 (plain cached A-reads; L2 dedupes the 64x redundancy) hardened:
//  - t-slab stride padded +4KB (SLAB_ = B*H + 2048 elems): a stream prefetch
//    running past slab t can no longer allocate head-of-slab-(t+1) lines into
//    a consumer L2 before the sc1 stores write them (the one concrete
//    within-dispatch staleness mechanism). sc1 stores don't invalidate remote
//    L2 lines, so pre-write allocation must be impossible -> pad kills it.
//  - staging loads widened to 16B uint4 (swizzle is 16B-granular): halves
//    load-transaction count on whichever path serves them.
// Safety recap: cross-dispatch stale lines killed by one-time
// fence(ACQUIRE,"agent") at kernel start; within-dispatch, every Hall line is
// written once (sc1, no L2 allocation) and first touched only after flag(t).
// Producer protocol unchanged from R5 (sc1 stores -> vmcnt drained at
// __syncthreads -> relaxed flag add). R3/R4 container deaths: infra (diff
// cannot fault or hang; see session journal).

typedef _Float16 half_t;
typedef _Float16 half8 __attribute__((ext_vector_type(8)));
typedef _Float16 half4v __attribute__((ext_vector_type(4)));
typedef float f32x4 __attribute__((ext_vector_type(4)));

#define B_ 128
#define H_ 1024
#define S_ 512
#define SLAB_ ((size_t)(B_ * H_ + 2048))   // elements; 4KB guard per t-slab

__device__ __forceinline__ float sigm(float x) {
  return 1.f / (1.f + __expf(-x));
}
__device__ __forceinline__ float tanh_fast(float x) {
  x = fminf(fmaxf(x, -15.f), 15.f);
  float e2 = __expf(2.f * x);
  return (e2 - 1.f) / (e2 + 1.f);
}

// ---------------- pack combined gate weights, split fp16 hi+lo ---------------
// Packed row p = j*4 + g: g0: Wir+Whr, g1: Wiz+Whz, g2: Win, g3: Whn.
// Per ntile (16 rows): half8 unit u = kq*64 + lane holds W[row nt*16+(lane&15)]
// [k = kq*32 + (lane>>4)*8 .. +7].
__global__ void k_pack(const float* __restrict__ Wih, const float* __restrict__ Whh,
                       half_t* __restrict__ Wpkh, half_t* __restrict__ Wpkl) {
  int tid = blockIdx.x * 256 + threadIdx.x;   // [0, 524288)
  int nt_g = tid >> 11;                       // [0,256)
  int u    = tid & 2047;
  int kq = u >> 6, lane = u & 63;
  int p = nt_g * 16 + (lane & 15);
  int j = p >> 2, g = p & 3;
  int k0 = kq * 32 + (lane >> 4) * 8;
  float v[8];
  if (g == 0) {
    const float* p0 = Wih + (size_t)j * H_ + k0;
    const float* p1 = Whh + (size_t)j * H_ + k0;
#pragma unroll
    for (int i = 0; i < 8; ++i) v[i] = p0[i] + p1[i];
  } else if (g == 1) {
    const float* p0 = Wih + (size_t)(1024 + j) * H_ + k0;
    const float* p1 = Whh + (size_t)(1024 + j) * H_ + k0;
#pragma unroll
    for (int i = 0; i < 8; ++i) v[i] = p0[i] + p1[i];
  } else if (g == 2) {
    const float* p0 = Wih + (size_t)(2048 + j) * H_ + k0;
#pragma unroll
    for (int i = 0; i < 8; ++i) v[i] = p0[i];
  } else {
    const float* p0 = Whh + (size_t)(2048 + j) * H_ + k0;
#pragma unroll
    for (int i = 0; i < 8; ++i) v[i] = p0[i];
  }
  half8 hv, lv;
#pragma unroll
  for (int i = 0; i < 8; ++i) {
    half_t h = (half_t)v[i];
    hv[i] = h;
    lv[i] = (half_t)(v[i] - (float)h);
  }
  size_t dst = (size_t)nt_g * 16384 + (size_t)u * 8;
  *(half8*)(Wpkh + dst) = hv;
  *(half8*)(Wpkl + dst) = lv;
}

// ---------------- fp32 -> fp16 conversion of enc_outputs --------------------
__global__ void k_enc(const float* __restrict__ src, half_t* __restrict__ dst) {
  size_t i = (size_t)blockIdx.x * 256 + threadIdx.x;
  const float4* s4 = (const float4*)src;
  float4 v = s4[i];
  half4v h;
  h[0] = (half_t)v.x; h[1] = (half_t)v.y; h[2] = (half_t)v.z; h[3] = (half_t)v.w;
  *(half4v*)(dst + i * 4) = h;
}

// ---------------- exact step 0 (x = 0, h = h0), fp64 accumulate --------------
__global__ void k_step0(const float* __restrict__ h0, const float* __restrict__ Whh,
                        const float* __restrict__ bih, const float* __restrict__ bhh,
                        float* __restrict__ Hst1, half_t* __restrict__ Hallh,
                        half_t* __restrict__ Halll) {
  __shared__ float wr[1024], wz[1024], wn[1024];
  int j = blockIdx.x;
  int b = threadIdx.x;
  for (int k = b; k < 1024; k += 128) {
    wr[k] = Whh[(size_t)j * H_ + k];
    wz[k] = Whh[(size_t)(1024 + j) * H_ + k];
    wn[k] = Whh[(size_t)(2048 + j) * H_ + k];
  }
  __syncthreads();
  const float* hb = h0 + (size_t)b * H_;
  double sr = 0.0, sz = 0.0, sn = 0.0;
  for (int k = 0; k < 1024; ++k) {
    double h = (double)hb[k];
    sr += h * (double)wr[k]; sz += h * (double)wz[k]; sn += h * (double)wn[k];
  }
  float r = sigm((float)sr + bih[j] + bhh[j]);
  float z = sigm((float)sz + bih[1024 + j] + bhh[1024 + j]);
  float n = tanhf(bih[2048 + j] + r * ((float)sn + bhh[2048 + j]));
  float h1 = (1.f - z) * n + z * hb[j];
  Hst1[(size_t)b * H_ + j] = h1;
  half_t hi = (half_t)h1;
  Hallh[SLAB_ + (size_t)b * H_ + j] = hi;
  Halll[SLAB_ + (size_t)b * H_ + j] = (half_t)(h1 - (float)hi);
}

// ---------------- persistent GRU scan, steps 1..511, split-fp16 --------------
// 256 blocks x 512 thr. bid: ab = bid&3 (batch group, 2 slices), jb = bid>>2
// (16 j's). Wave wv: ntl = wv&3 (4-j subtile), sll = wv>>2 -> slice ab*2+sll.
// Per step: block stages A (h[t] rows ab*32..+31, hi+lo, 128 KB) into LDS via
// PLAIN cached 16B loads (L2 absorbs the 64x redundancy) with XOR-swizzled
// source addressing; W-hi streams from global (cached); W-lo in registers.
// h published via relaxed-agent sc1 atomic stores; flag add relaxed after
// __syncthreads.
__global__ void __launch_bounds__(512, 2)
k_gru(const half_t* __restrict__ Wpkh, const half_t* __restrict__ Wpkl,
      const float* __restrict__ Hst1, half_t* __restrict__ Hallh,
      half_t* __restrict__ Halll, const float* __restrict__ bih,
      const float* __restrict__ bhh, int* __restrict__ flags) {
  extern __shared__ char smem[];           // 128 KB: A_hi[32][2048B] | A_lo
  // One-time agent acquire: invalidate any stale L1/L2 lines surviving from
  // previous dispatches (bench iterations).
  __builtin_amdgcn_fence(__ATOMIC_ACQUIRE, "agent");

  const int bid = blockIdx.x;
  const int ab = bid & 3, jb = bid >> 2;
  const int tid = threadIdx.x;
  const int wv = tid >> 6, lane = tid & 63;
  const int ntl = wv & 3, sll = wv >> 2;
  const int sl = ab * 2 + sll;
  const int jl = lane & 15, quad = lane >> 4, jj = jl >> 2;

  // W-lo -> registers (this wave's ntile)
  half8 Wlo[32];
  {
    const half_t* src = Wpkl + (size_t)(jb * 4 + ntl) * 16384 + (size_t)lane * 8;
#pragma unroll
    for (int kq = 0; kq < 32; ++kq)
      Wlo[kq] = *(const half8*)(src + (size_t)kq * 512);
  }
  // W-hi global stream base (plain cached loads; constant data)
  const half_t* Wg = Wpkh + (size_t)(jb * 4 + ntl) * 16384 + (size_t)lane * 8;

  const int j = jb * 16 + ntl * 4 + jj;
  const float br  = bih[j]        + bhh[j];
  const float bz  = bih[1024 + j] + bhh[1024 + j];
  const float bxn = bih[2048 + j];
  const float bhn = bhh[2048 + j];

  float hold[4];
#pragma unroll
  for (int r = 0; r < 4; ++r)
    hold[r] = Hst1[(size_t)(sl * 16 + quad * 4 + r) * H_ + j];

  const int qb = lane & 48;                // quad*16
  const int j0 = jb * 16 + ntl * 4;

  // A-read bases: logical (row = sll*16+jl, colbyte = quad*16 + kq*64),
  // swizzled LDS offset = row*2048 + ((quad*16 | kq*64) ^ ((jl&7)<<4)).
  // Split: bits4-5 fold into the base; bit6 flips kq parity -> even/odd bases.
  const int arow = sll * 16 + jl;
  const int a0   = arow * 2048 + ((quad * 16) ^ ((jl & 3) << 4));
  const int sx   = (jl >> 2) & 1;
  const char* pAhE = smem + a0 + sx * 64;          // even kq
  const char* pAhO = smem + a0 - sx * 64;          // odd  kq
  const char* pAlE = pAhE + 65536;
  const char* pAlO = pAhO + 65536;

  // stage addressing (16B units): unit u16 = c*512 + tid, row r = u16>>7,
  // in-row byte = (u16&127)*16, source col = in-row ^ ((r&7)<<4).
  const int so16 = (tid & 127) * 16;
  const int r_hi = tid >> 7;               // 0..3

  for (int t = 1; t < 512; ++t) {
    if (t >= 2) {
      int* f = flags + t * 8 + ab * 2;
      while (__hip_atomic_load(f, __ATOMIC_RELAXED, __HIP_MEMORY_SCOPE_AGENT) < 64)
        __builtin_amdgcn_s_sleep(1);
      while (__hip_atomic_load(f + 1, __ATOMIC_RELAXED, __HIP_MEMORY_SCOPE_AGENT) < 64)
        __builtin_amdgcn_s_sleep(1);
      __builtin_amdgcn_fence(__ATOMIC_ACQUIRE, "workgroup");
    }
    // ---- stage A(t): 128 KB via plain cached 16B loads, linear ds_write ----
    {
      const size_t tb = ((size_t)t * SLAB_ + (size_t)ab * 32 * H_) * 2;  // bytes
      uint4 hv[8], lv[8];
#pragma unroll
      for (int c = 0; c < 8; ++c) {
        const int r = c * 4 + r_hi;
        const size_t srcoff = tb + (size_t)r * 2048 + (size_t)(so16 ^ ((r & 7) << 4));
        hv[c] = *(const uint4*)((const char*)Hallh + srcoff);
        lv[c] = *(const uint4*)((const char*)Halll + srcoff);
      }
#pragma unroll
      for (int c = 0; c < 8; ++c) {
        *(uint4*)(smem + (size_t)(c * 512 + tid) * 16) = hv[c];
        *(uint4*)(smem + 65536 + (size_t)(c * 512 + tid) * 16) = lv[c];
      }
    }
    __syncthreads();

    f32x4 acc_a = {0.f,0.f,0.f,0.f};
    f32x4 acc_b = {0.f,0.f,0.f,0.f};
    f32x4 acc_c = {0.f,0.f,0.f,0.f};
#pragma unroll
    for (int kq = 0; kq < 32; ++kq) {
      const char* pA = (kq & 1) ? pAhO : pAhE;
      const char* pL = (kq & 1) ? pAlO : pAlE;
      half8 ah = *(const half8*)(pA + kq * 64);
      half8 al = *(const half8*)(pL + kq * 64);
      half8 bh = *(const half8*)(Wg + (size_t)kq * 512);
      acc_a = __builtin_amdgcn_mfma_f32_16x16x32_f16(ah, bh,      acc_a, 0, 0, 0);
      acc_b = __builtin_amdgcn_mfma_f32_16x16x32_f16(al, bh,      acc_b, 0, 0, 0);
      acc_c = __builtin_amdgcn_mfma_f32_16x16x32_f16(ah, Wlo[kq], acc_c, 0, 0, 0);
    }

    half_t* Hh = Hallh + (size_t)(t + 1) * SLAB_;
    half_t* Hl = Halll + (size_t)(t + 1) * SLAB_;
#pragma unroll
    for (int r = 0; r < 4; ++r) {
      float v = acc_a[r] + acc_b[r] + acc_c[r];
      int base = lane & 60;
      float g0 = __shfl(v, base | 0);
      float g1 = __shfl(v, base | 1);
      float g2 = __shfl(v, base | 2);
      float g3 = __shfl(v, base | 3);
      float rr = sigm(g0 + br);
      float zz = sigm(g1 + bz);
      float nn = tanh_fast(g2 + bxn + rr * (g3 + bhn));
      float h = (1.f - zz) * nn + zz * hold[r];
      hold[r] = h;
      half_t hi = (half_t)h;
      half_t lo = (half_t)(h - (float)hi);
      unsigned hb16 = (unsigned)__builtin_bit_cast(unsigned short, hi);
      unsigned lb16 = (unsigned)__builtin_bit_cast(unsigned short, lo);
      unsigned hp0 = __shfl(hb16, qb | 0) | (__shfl(hb16, qb | 4) << 16);
      unsigned hp1 = __shfl(hb16, qb | 8) | (__shfl(hb16, qb | 12) << 16);
      unsigned lp0 = __shfl(lb16, qb | 0) | (__shfl(lb16, qb | 4) << 16);
      unsigned lp1 = __shfl(lb16, qb | 8) | (__shfl(lb16, qb | 12) << 16);
      if (jl == 0) {
        int brow = sl * 16 + quad * 4 + r;
        unsigned long long hp = (unsigned long long)hp0 | ((unsigned long long)hp1 << 32);
        unsigned long long lp = (unsigned long long)lp0 | ((unsigned long long)lp1 << 32);
        __hip_atomic_store((unsigned long long*)(Hh + (size_t)brow * H_ + j0), hp,
                           __ATOMIC_RELAXED, __HIP_MEMORY_SCOPE_AGENT);
        __hip_atomic_store((unsigned long long*)(Hl + (size_t)brow * H_ + j0), lp,
                           __ATOMIC_RELAXED, __HIP_MEMORY_SCOPE_AGENT);
      }
    }
    __syncthreads();   // drains vmcnt: all waves' sc1 stores performed at the
                       // agent coherence point before the flag is bumped.
    if (tid < 2)
      __hip_atomic_fetch_add(flags + (t + 1) * 8 + ab * 2 + tid, 1,
                             __ATOMIC_RELAXED, __HIP_MEMORY_SCOPE_AGENT);
  }
}

// ---------------- scores + softmax ------------------------------------------
__global__ void __launch_bounds__(512, 1)
k_scores(const half_t* __restrict__ Hallh, const half_t* __restrict__ enc16,
         const int* __restrict__ lengths, half_t* __restrict__ wbuf) {
  extern __shared__ char sm[];
  const int b = blockIdx.x, tt = blockIdx.y;
  const int tid = threadIdx.x;
  const int w = tid >> 6, lane = tid & 63;
  const int jl = lane & 15, quad = lane >> 4;
  const int t0 = tt * 128;
  const int len = lengths[b];

  f32x4 acc[32];
#pragma unroll
  for (int i = 0; i < 32; ++i) acc[i] = (f32x4){0.f,0.f,0.f,0.f};

  const half_t* Arow =
      Hallh + (size_t)(1 + t0 + w * 16 + jl) * SLAB_ + (size_t)b * H_ + quad * 8;

  uint4* smu = (uint4*)sm;
  const int s = tid;
  const uint4* grow = (const uint4*)(enc16 + ((size_t)s * B_ + b) * H_);
  uint4* dbase = smu + ((s >> 4) * 64 + (s & 15));

  { uint4* d = dbase; d[0] = grow[0]; d[16] = grow[1]; d[32] = grow[2]; d[48] = grow[3]; }
  uint4 a_cur = *(const uint4*)(Arow);
  __syncthreads();

  for (int kq = 0; kq < 32; ++kq) {
    const int buf = kq & 1;
    uint4 a_next;
    if (kq < 31) {
      const uint4* g = grow + (kq + 1) * 4;
      uint4* d = dbase + (buf ^ 1) * 2048;
      d[0] = g[0]; d[16] = g[1]; d[32] = g[2]; d[48] = g[3];
      a_next = *(const uint4*)(Arow + (kq + 1) * 32);
    }
    half8 av = __builtin_bit_cast(half8, a_cur);
    const half8* Bb = (const half8*)sm + buf * 2048 + lane;
#pragma unroll
    for (int nf = 0; nf < 32; ++nf)
      acc[nf] = __builtin_amdgcn_mfma_f32_16x16x32_f16(av, Bb[nf * 64], acc[nf], 0, 0, 0);
    a_cur = a_next;
    __syncthreads();
  }

#pragma unroll
  for (int r = 0; r < 4; ++r) {
    float vmax = -3.0e38f;
#pragma unroll
    for (int nf = 0; nf < 32; ++nf) {
      int scol = nf * 16 + jl;
      float v = (scol < len) ? acc[nf][r] : -3.0e38f;
      acc[nf][r] = v;
      vmax = fmaxf(vmax, v);
    }
#pragma unroll
    for (int off = 1; off < 16; off <<= 1) vmax = fmaxf(vmax, __shfl_xor(vmax, off, 64));
    float esum = 0.f;
#pragma unroll
    for (int nf = 0; nf < 32; ++nf) {
      float e = __expf(acc[nf][r] - vmax);
      acc[nf][r] = e;
      esum += e;
    }
#pragma unroll
    for (int off = 1; off < 16; off <<= 1) esum += __shfl_xor(esum, off, 64);
    float inv = 1.f / esum;
    const int t = t0 + w * 16 + quad * 4 + r;
    half_t* wrow = wbuf + ((size_t)b * S_ + t) * S_ + jl;
#pragma unroll
    for (int nf = 0; nf < 32; ++nf) wrow[nf * 16] = (half_t)(acc[nf][r] * inv);
  }
}

// ---------------- context GEMM + projection (context part) ------------------
__global__ void __launch_bounds__(512, 1)
k_ctx(const half_t* __restrict__ wbuf, const half_t* __restrict__ enc16,
      const float* __restrict__ Wp, float* __restrict__ out) {
  extern __shared__ char sm[];
  const int b = blockIdx.x, ht = blockIdx.y, tt = blockIdx.z;
  const int tid = threadIdx.x;
  const int w = tid >> 6, lane = tid & 63;
  const int jl = lane & 15, quad = lane >> 4;
  const int h0 = ht * 128, t0 = tt * 128;

  f32x4 acc[8];
#pragma unroll
  for (int i = 0; i < 8; ++i) acc[i] = (f32x4){0.f,0.f,0.f,0.f};

  const half_t* Arow = wbuf + ((size_t)b * S_ + t0 + w * 16 + jl) * S_ + quad * 8;
  const int s_l = tid >> 4, hc = tid & 15;
  const half_t* gsrc = enc16 + ((size_t)s_l * B_ + b) * H_ + h0 + hc * 8;
  half_t* sbase = (half_t*)sm;

  {
    uint4 v = *(const uint4*)gsrc;
    half8 hv = __builtin_bit_cast(half8, v);
#pragma unroll
    for (int i = 0; i < 8; ++i) {
      int h_l = hc * 8 + i;
      sbase[((h_l >> 4) * 64 + (s_l >> 3) * 16 + (h_l & 15)) * 8 + (s_l & 7)] = hv[i];
    }
  }
  uint4 a_cur = *(const uint4*)(Arow);
  __syncthreads();

  for (int kq = 0; kq < 16; ++kq) {
    const int buf = kq & 1;
    uint4 a_next;
    if (kq < 15) {
      uint4 v = *(const uint4*)(gsrc + (size_t)(kq + 1) * 32 * (B_ * H_));
      half8 hv = __builtin_bit_cast(half8, v);
      half_t* d = sbase + (buf ^ 1) * 4096;
#pragma unroll
      for (int i = 0; i < 8; ++i) {
        int h_l = hc * 8 + i;
        d[((h_l >> 4) * 64 + (s_l >> 3) * 16 + (h_l & 15)) * 8 + (s_l & 7)] = hv[i];
      }
      a_next = *(const uint4*)(Arow + (kq + 1) * 32);
    }
    half8 av = __builtin_bit_cast(half8, a_cur);
    const half8* Bb = (const half8*)sm + buf * 512 + lane;
#pragma unroll
    for (int nf = 0; nf < 8; ++nf)
      acc[nf] = __builtin_amdgcn_mfma_f32_16x16x32_f16(av, Bb[nf * 64], acc[nf], 0, 0, 0);
    a_cur = a_next;
    __syncthreads();
  }

  float wp0[8], wp1[8];
#pragma unroll
  for (int nf = 0; nf < 8; ++nf) {
    int h = h0 + nf * 16 + jl;
    wp0[nf] = Wp[h];
    wp1[nf] = Wp[2048 + h];
  }
#pragma unroll
  for (int r = 0; r < 4; ++r) {
    float y0 = 0.f, y1 = 0.f;
#pragma unroll
    for (int nf = 0; nf < 8; ++nf) {
      y0 += acc[nf][r] * wp0[nf];
      y1 += acc[nf][r] * wp1[nf];
    }
#pragma unroll
    for (int off = 1; off < 16; off <<= 1) {
      y0 += __shfl_xor(y0, off, 64);
      y1 += __shfl_xor(y1, off, 64);
    }
    if (jl == 0) {
      int t = t0 + w * 16 + quad * 4 + r;
      float* o = out + ((size_t)b * S_ + t) * 2;
      atomicAdd(o, y0);
      atomicAdd(o + 1, y1);
    }
  }
}

// ---------------- projection, h part + bias ----------------------------------
__global__ void k_ph(const half_t* __restrict__ Hallh, const float* __restrict__ Wp,
                     const float* __restrict__ bp, float* __restrict__ out) {
  const int t = blockIdx.x, b = blockIdx.y;
  const int tid = threadIdx.x;  // 128
  const half_t* hrow = Hallh + (size_t)(1 + t) * SLAB_ + (size_t)b * H_;
  float y0 = 0.f, y1 = 0.f;
#pragma unroll
  for (int k = 0; k < 8; ++k) {
    int h = tid + k * 128;
    float hv = (float)hrow[h];
    y0 += hv * Wp[1024 + h];
    y1 += hv * Wp[3072 + h];
  }
  for (int off = 1; off < 64; off <<= 1) {
    y0 += __shfl_xor(y0, off, 64);
    y1 += __shfl_xor(y1, off, 64);
  }
  __shared__ float red[4];
  int wid = tid >> 6;
  if ((tid & 63) == 0) { red[wid * 2] = y0; red[wid * 2 + 1] = y1; }
  __syncthreads();
  if (tid == 0) {
    size_t o = ((size_t)b * S_ + t) * 2;
    out[o]     += red[0] + red[2] + bp[0];
    out[o + 1] += red[1] + red[3] + bp[1];
  }
}

// ---------------- host launcher ----------------------------------------------
extern "C" void kernel_launch(void* const* d_in, const int* in_sizes, int n_in,
                              void* d_out, int out_size, void* d_ws, size_t ws_size,
                              hipStream_t stream) {
  const float* enc  = (const float*)d_in[0];
  const float* h0   = (const float*)d_in[1];
  const float* Wih  = (const float*)d_in[2];
  const float* Whh  = (const float*)d_in[3];
  const float* bih  = (const float*)d_in[4];
  const float* bhh  = (const float*)d_in[5];
  const float* Wp   = (const float*)d_in[6];
  const float* bp   = (const float*)d_in[7];
  const int* lengths = (const int*)d_in[8];
  float* out = (float*)d_out;

  char* ws = (char*)d_ws;
  size_t off = 0;
  auto alloc = [&](size_t bytes) -> char* {
    char* p = ws + off;
    off = (off + bytes + 511) & ~(size_t)511;
    return p;
  };
  half_t* Wpkh  = (half_t*)alloc((size_t)4096 * 1024 * 2);       // 8.39 MB
  half_t* Wpkl  = (half_t*)alloc((size_t)4096 * 1024 * 2);       // 8.39 MB
  int*    flags = (int*)alloc((size_t)513 * 8 * 4);
  float*  Hst1  = (float*)alloc((size_t)B_ * H_ * 4);            // 0.5 MB
  half_t* Hallh = (half_t*)alloc((size_t)513 * SLAB_ * 2);       // 136.6 MB
  half_t* Halll = (half_t*)alloc((size_t)513 * SLAB_ * 2);       // 136.6 MB
  half_t* enc16 = (half_t*)alloc((size_t)S_ * B_ * H_ * 2);      // 134.2 MB
  half_t* wbuf  = (half_t*)alloc((size_t)B_ * S_ * S_ * 2);      // 67.1 MB
  (void)ws_size; (void)in_sizes; (void)n_in;

  hipMemsetAsync(flags, 0, (size_t)513 * 8 * 4, stream);
  hipMemsetAsync(out, 0, (size_t)out_size * 4, stream);

  k_pack<<<2048, 256, 0, stream>>>(Wih, Whh, Wpkh, Wpkl);
  k_enc<<<65536, 256, 0, stream>>>(enc, enc16);
  k_step0<<<1024, 128, 0, stream>>>(h0, Whh, bih, bhh, Hst1, Hallh, Halll);

  hipFuncSetAttribute((const void*)k_gru,
                      hipFuncAttributeMaxDynamicSharedMemorySize, 131072);
  k_gru<<<256, 512, 131072, stream>>>(Wpkh, Wpkl, Hst1, Hallh, Halll, bih, bhh, flags);

  hipFuncSetAttribute((const void*)k_scores,
                      hipFuncAttributeMaxDynamicSharedMemorySize, 65536);
  k_scores<<<dim3(128, 4), 512, 65536, stream>>>(Hallh, enc16, lengths, wbuf);
  k_ctx<<<dim3(128, 8, 4), 512, 16384, stream>>>(wbuf, enc16, Wp, out);
  k_ph<<<dim3(512, 128), 128, 0, stream>>>(Hallh, Wp, bp, out);
}